// Round 1
// baseline (249.861 us; speedup 1.0000x reference)
//
#include <hip/hip_runtime.h>
#include <hip/hip_bf16.h>

#define NB 4
#define NS 4096
#define ND 1024
#define LN_EPS 1e-5f

#define BM 128
#define BN 128
#define BK 32

typedef __bf16 bf16x8 __attribute__((ext_vector_type(8)));
typedef float f32x4 __attribute__((ext_vector_type(4)));

__device__ __forceinline__ unsigned short f2bf(float f) {
  unsigned int u = __float_as_uint(f);
  u += 0x7FFFu + ((u >> 16) & 1u);   // round-to-nearest-even
  return (unsigned short)(u >> 16);
}

// ---- kernel 1: g[d] = (1/NS) * sum_f fk[f] * cos(2*pi*f*d/NS)
__global__ void kgcirc(const float* __restrict__ fk, float* __restrict__ g) {
  const int d = blockIdx.x;
  const int t = threadIdx.x;
  float acc = 0.f;
  const float c = 6.283185307179586f / (float)NS;
  for (int f = t; f < NS; f += 256) {
    int ph = (f * d) & (NS - 1);              // exact integer phase reduction
    acc += fk[f] * cosf(c * (float)ph);
  }
  #pragma unroll
  for (int off = 32; off; off >>= 1) acc += __shfl_xor(acc, off);
  __shared__ float red[4];
  if ((t & 63) == 0) red[t >> 6] = acc;
  __syncthreads();
  if (t == 0) g[d] = (red[0] + red[1] + red[2] + red[3]) * (1.0f / (float)NS);
}

// ---- kernel 2: G[n][m] = bf16(g[(n-m) mod NS])
__global__ void kbuildG(const float* __restrict__ g, unsigned short* __restrict__ G) {
  const int n = blockIdx.x;
  unsigned short* row = G + (size_t)n * NS;
  for (int m = threadIdx.x; m < NS; m += 256)
    row[m] = f2bf(g[(n - m) & (NS - 1)]);
}

// ---- kernel 3: xT[b][d][s] = bf16(x[b][s][d])  (tiled transpose + cast)
__global__ void ktrans(const float* __restrict__ x, unsigned short* __restrict__ xT) {
  __shared__ float tile[64][65];
  const int b = blockIdx.z;
  const int s0 = blockIdx.x * 64;
  const int d0 = blockIdx.y * 64;
  const int t = threadIdx.x;
  const float* xb = x + (size_t)b * NS * ND;
  #pragma unroll
  for (int p = 0; p < 4; ++p) {
    int r = (t >> 4) + p * 16;
    int c = (t & 15) * 4;
    float4 v = *reinterpret_cast<const float4*>(xb + (size_t)(s0 + r) * ND + (d0 + c));
    tile[r][c] = v.x; tile[r][c + 1] = v.y; tile[r][c + 2] = v.z; tile[r][c + 3] = v.w;
  }
  __syncthreads();
  unsigned short* xTb = xT + (size_t)b * ND * NS;
  #pragma unroll
  for (int p = 0; p < 2; ++p) {
    int dr = (t >> 3) + p * 32;
    int sc = (t & 7) * 8;
    union { unsigned short u16[8]; uint4 v; } pk;
    #pragma unroll
    for (int j = 0; j < 8; ++j) pk.u16[j] = f2bf(tile[sc + j][dr]);
    *reinterpret_cast<uint4*>(xTb + (size_t)(d0 + dr) * NS + (s0 + sc)) = pk.v;
  }
}

// ---- kernel 4: batched GEMM  filtered[b] = G (MxK) @ x_b  via A/B^T bf16 MFMA
__device__ __forceinline__ void gload16(const void* gp, void* lp) {
  __builtin_amdgcn_global_load_lds(
      (__attribute__((address_space(1))) void*)gp,
      (__attribute__((address_space(3))) void*)lp, 16, 0, 0);
}

__global__ __launch_bounds__(256) void kgemm(const unsigned short* __restrict__ Gm,
                                             const unsigned short* __restrict__ xT,
                                             float* __restrict__ out) {
  __shared__ __align__(16) unsigned short lA[BM * BK];  // 8 KiB
  __shared__ __align__(16) unsigned short lB[BN * BK];  // 8 KiB
  const int t = threadIdx.x;
  const int lane = t & 63;
  const int wave = t >> 6;
  const int wr = wave >> 1, wc = wave & 1;   // 2x2 waves -> 64x64 each
  const int n0 = blockIdx.x * BM;
  const int d0 = blockIdx.y * BN;
  const unsigned short* Ab = Gm;                                   // [NS][NS]
  const unsigned short* Bb = xT + (size_t)blockIdx.z * ND * NS;    // [ND][NS]
  float* Cb = out + (size_t)blockIdx.z * NS * ND;

  const int idx0 = t;         // staging slot, round 0
  const int idx1 = t + 256;   // round 1
  const int row0 = idx0 >> 2, col0 = (idx0 & 3) * 8;
  const int row1 = idx1 >> 2, col1 = (idx1 & 3) * 8;

  const int kq = lane >> 4;   // k-block 0..3
  const int rl = lane & 15;   // fragment row/col

  f32x4 acc[4][4] = {};

  for (int kt = 0; kt < NS; kt += BK) {
    gload16(Ab + (size_t)(n0 + row0) * NS + kt + col0, &lA[idx0 * 8]);
    gload16(Ab + (size_t)(n0 + row1) * NS + kt + col1, &lA[idx1 * 8]);
    gload16(Bb + (size_t)(d0 + row0) * NS + kt + col0, &lB[idx0 * 8]);
    gload16(Bb + (size_t)(d0 + row1) * NS + kt + col1, &lB[idx1 * 8]);
    __syncthreads();          // drains vmcnt (global_load_lds) + barrier
    bf16x8 af[4], bfr[4];
    #pragma unroll
    for (int i = 0; i < 4; ++i) {
      af[i]  = *reinterpret_cast<const bf16x8*>(&lA[(wr * 64 + i * 16 + rl) * BK + kq * 8]);
      bfr[i] = *reinterpret_cast<const bf16x8*>(&lB[(wc * 64 + i * 16 + rl) * BK + kq * 8]);
    }
    #pragma unroll
    for (int i = 0; i < 4; ++i)
      #pragma unroll
      for (int j = 0; j < 4; ++j)
        acc[i][j] = __builtin_amdgcn_mfma_f32_16x16x32_bf16(af[i], bfr[j], acc[i][j], 0, 0, 0);
    __syncthreads();          // protect LDS before next stage
  }

  #pragma unroll
  for (int i = 0; i < 4; ++i) {
    const int nb = n0 + wr * 64 + i * 16 + (lane >> 4) * 4;
    #pragma unroll
    for (int j = 0; j < 4; ++j) {
      const int dc = d0 + wc * 64 + j * 16 + (lane & 15);
      #pragma unroll
      for (int rg = 0; rg < 4; ++rg)
        Cb[(size_t)(nb + rg) * ND + dc] = acc[i][j][rg];   // C/D: col=lane&15, row=(lane>>4)*4+rg
    }
  }
}

// ---- kernel 5: in-place quaternion rotation + LayerNorm over D (one block per (b,s) row)
__global__ __launch_bounds__(256) void krotln(float* __restrict__ io,
                                              const float* __restrict__ R,
                                              const float* __restrict__ gam,
                                              const float* __restrict__ bet) {
  const int t = threadIdx.x;
  float* p = io + (size_t)blockIdx.x * ND + t * 4;
  float4 v = *reinterpret_cast<const float4*>(p);
  float o0 = R[0] * v.x + R[1] * v.y + R[2]  * v.z + R[3]  * v.w;
  float o1 = R[4] * v.x + R[5] * v.y + R[6]  * v.z + R[7]  * v.w;
  float o2 = R[8] * v.x + R[9] * v.y + R[10] * v.z + R[11] * v.w;
  float o3 = R[12] * v.x + R[13] * v.y + R[14] * v.z + R[15] * v.w;
  float sm = o0 + o1 + o2 + o3;
  float sq = o0 * o0 + o1 * o1 + o2 * o2 + o3 * o3;
  #pragma unroll
  for (int off = 32; off; off >>= 1) {
    sm += __shfl_xor(sm, off);
    sq += __shfl_xor(sq, off);
  }
  __shared__ float rs[4], rq[4];
  if ((t & 63) == 0) { rs[t >> 6] = sm; rq[t >> 6] = sq; }
  __syncthreads();
  sm = rs[0] + rs[1] + rs[2] + rs[3];
  sq = rq[0] + rq[1] + rq[2] + rq[3];
  const float mean = sm * (1.0f / ND);
  const float var = sq * (1.0f / ND) - mean * mean;
  const float inv = rsqrtf(var + LN_EPS);
  const float4 gv = *reinterpret_cast<const float4*>(gam + t * 4);
  const float4 bv = *reinterpret_cast<const float4*>(bet + t * 4);
  float4 r;
  r.x = (o0 - mean) * inv * gv.x + bv.x;
  r.y = (o1 - mean) * inv * gv.y + bv.y;
  r.z = (o2 - mean) * inv * gv.z + bv.z;
  r.w = (o3 - mean) * inv * gv.w + bv.w;
  *reinterpret_cast<float4*>(p) = r;
}

extern "C" void kernel_launch(void* const* d_in, const int* in_sizes, int n_in,
                              void* d_out, int out_size, void* d_ws, size_t ws_size,
                              hipStream_t stream) {
  const float* x  = (const float*)d_in[0];
  const float* R  = (const float*)d_in[1];
  const float* fk = (const float*)d_in[2];
  const float* gm = (const float*)d_in[3];
  const float* bt = (const float*)d_in[4];
  float* out = (float*)d_out;

  char* ws = (char*)d_ws;
  unsigned short* G  = (unsigned short*)ws;                                   // 32 MiB
  unsigned short* xT = (unsigned short*)(ws + (size_t)NS * NS * 2);           // 32 MiB
  float* g = (float*)(ws + (size_t)NS * NS * 2 + (size_t)NB * ND * NS * 2);   // 16 KiB

  kgcirc<<<NS, 256, 0, stream>>>(fk, g);
  kbuildG<<<NS, 256, 0, stream>>>(g, G);
  ktrans<<<dim3(NS / 64, ND / 64, NB), 256, 0, stream>>>(x, xT);
  kgemm<<<dim3(NS / BM, ND / BN, NB), 256, 0, stream>>>(G, xT, out);  // fp32 "filtered" -> d_out
  krotln<<<NB * NS, 256, 0, stream>>>(out, R, gm, bt);                // in-place rotate + LN
}

// Round 2
// 175.904 us; speedup vs baseline: 1.4204x; 1.4204x over previous
//
#include <hip/hip_runtime.h>
#include <hip/hip_bf16.h>

#define NB 4
#define NS 4096
#define ND 1024
#define LN_EPS 1e-5f

#define BK2 32
#define NT2 (NS / BK2)   // 128 K-tiles

typedef __bf16 bf16x8 __attribute__((ext_vector_type(8)));
typedef float f32x4 __attribute__((ext_vector_type(4)));

__device__ __forceinline__ unsigned short f2bf(float f) {
  unsigned int u = __float_as_uint(f);
  u += 0x7FFFu + ((u >> 16) & 1u);   // round-to-nearest-even
  return (unsigned short)(u >> 16);
}

// ---- kernel 1: g[d] = (1/NS) * sum_f fk[f] * cos(2*pi*f*d/NS)
__global__ void kgcirc(const float* __restrict__ fk, float* __restrict__ g) {
  const int d = blockIdx.x;
  const int t = threadIdx.x;
  float acc = 0.f;
  const float c = 6.283185307179586f / (float)NS;
  for (int f = t; f < NS; f += 256) {
    int ph = (f * d) & (NS - 1);              // exact integer phase reduction
    acc += fk[f] * cosf(c * (float)ph);
  }
  #pragma unroll
  for (int off = 32; off; off >>= 1) acc += __shfl_xor(acc, off);
  __shared__ float red[4];
  if ((t & 63) == 0) red[t >> 6] = acc;
  __syncthreads();
  if (t == 0) g[d] = (red[0] + red[1] + red[2] + red[3]) * (1.0f / (float)NS);
}

// ---- kernel 2: G[n][m] = bf16(g[(n-m) mod NS])
__global__ void kbuildG(const float* __restrict__ g, unsigned short* __restrict__ G) {
  const int n = blockIdx.x;
  unsigned short* row = G + (size_t)n * NS;
  for (int m = threadIdx.x; m < NS; m += 256)
    row[m] = f2bf(g[(n - m) & (NS - 1)]);
}

// ---- kernel 3: xT[b][d][s] = bf16(x[b][s][d])  (tiled transpose + cast)
__global__ void ktrans(const float* __restrict__ x, unsigned short* __restrict__ xT) {
  __shared__ float tile[64][65];
  const int b = blockIdx.z;
  const int s0 = blockIdx.x * 64;
  const int d0 = blockIdx.y * 64;
  const int t = threadIdx.x;
  const float* xb = x + (size_t)b * NS * ND;
  #pragma unroll
  for (int p = 0; p < 4; ++p) {
    int r = (t >> 4) + p * 16;
    int c = (t & 15) * 4;
    float4 v = *reinterpret_cast<const float4*>(xb + (size_t)(s0 + r) * ND + (d0 + c));
    tile[r][c] = v.x; tile[r][c + 1] = v.y; tile[r][c + 2] = v.z; tile[r][c + 3] = v.w;
  }
  __syncthreads();
  unsigned short* xTb = xT + (size_t)b * ND * NS;
  #pragma unroll
  for (int p = 0; p < 2; ++p) {
    int dr = (t >> 3) + p * 32;
    int sc = (t & 7) * 8;
    union { unsigned short u16[8]; uint4 v; } pk;
    #pragma unroll
    for (int j = 0; j < 8; ++j) pk.u16[j] = f2bf(tile[sc + j][dr]);
    *reinterpret_cast<uint4*>(xTb + (size_t)(d0 + dr) * NS + (s0 + sc)) = pk.v;
  }
}

// ---- async global->LDS (16B, literal size)
__device__ __forceinline__ void gload16(const void* gp, void* lp) {
  __builtin_amdgcn_global_load_lds(
      (__attribute__((address_space(1))) void*)gp,
      (__attribute__((address_space(3))) void*)lp, 16, 0, 0);
}

// ---- kernel 4: batched GEMM  filtered[b] = G (MxK) @ x_b^T, 256x256 tile,
//      ring-4 LDS K-tile buffers, counted vmcnt, XOR-swizzled LDS, setprio MFMA.
__global__ __launch_bounds__(512, 2) void kgemm2(const unsigned short* __restrict__ Gm,
                                                 const unsigned short* __restrict__ xT,
                                                 float* __restrict__ out) {
  extern __shared__ __align__(16) unsigned short lds[];  // 4 bufs x (A 8192 + B 8192) elems = 128 KiB
  const int t = threadIdx.x;
  const int lane = t & 63;
  const int wave = t >> 6;          // 0..7
  const int wr = wave >> 2;         // 0..1  -> 128-row half
  const int wc = wave & 3;          // 0..3  -> 64-col slice
  const int n0 = blockIdx.x * 256;  // S rows (output rows)
  const int d0 = blockIdx.y * 256;  // D cols
  const unsigned short* Ab = Gm;                                  // [NS][NS]
  const unsigned short* Bb = xT + (size_t)blockIdx.z * ND * NS;   // [ND][NS]
  float* Cb = out + (size_t)blockIdx.z * NS * ND;

  const int rl = lane & 15;
  const int kq = lane >> 4;
  const int kqs = kq ^ ((rl >> 1) & 3);           // read-side swizzled k-slot

  const int srow = t >> 2;                        // staging row (0..127), +128 for 2nd load
  const int scol = ((t & 3) ^ ((t >> 3) & 3)) * 8;  // pre-swizzled global column (elems)

  f32x4 acc[8][4] = {};

  const int aoff = (wr * 128 + rl) * BK2 + kqs * 8;  // A frag base (elems, within A buf)
  const int boff = (wc * 64 + rl) * BK2 + kqs * 8;   // B frag base (within B buf)

#define STAGE_A(Ts, bs) do { \
    gload16(Ab + (size_t)(n0 + srow) * NS + (size_t)(Ts) * BK2 + scol, \
            lds + (size_t)(bs) * 16384 + (size_t)t * 8); \
    gload16(Ab + (size_t)(n0 + 128 + srow) * NS + (size_t)(Ts) * BK2 + scol, \
            lds + (size_t)(bs) * 16384 + 4096 + (size_t)t * 8); \
  } while (0)
#define STAGE_B(Ts, bs) do { \
    gload16(Bb + (size_t)(d0 + srow) * NS + (size_t)(Ts) * BK2 + scol, \
            lds + (size_t)(bs) * 16384 + 8192 + (size_t)t * 8); \
    gload16(Bb + (size_t)(d0 + 128 + srow) * NS + (size_t)(Ts) * BK2 + scol, \
            lds + (size_t)(bs) * 16384 + 12288 + (size_t)t * 8); \
  } while (0)

  // prologue: tiles 0 and 1 in flight; retire tile 0 (own loads) then barrier
  STAGE_A(0, 0); STAGE_B(0, 0);
  STAGE_A(1, 1); STAGE_B(1, 1);
  asm volatile("s_waitcnt vmcnt(4)" ::: "memory");
  __builtin_amdgcn_s_barrier();

  for (int T = 0; T < NT2; ++T) {
    const int b = T & 3;
    const int bs = (T + 2) & 3;                       // stage target slot
    const int Ts = (T + 2 < NT2) ? (T + 2) : (NT2 - 1);  // clamp: keeps vmcnt arithmetic exact
    const unsigned short* Abuf = lds + (size_t)b * 16384;
    const unsigned short* Bbuf = Abuf + 8192;

    bf16x8 af[4], bfr[4];
    // ---- phase 0: rows 0-63 of wave half, all 4 B col-frags
    #pragma unroll
    for (int m = 0; m < 4; ++m)
      af[m] = *reinterpret_cast<const bf16x8*>(Abuf + aoff + m * 16 * BK2);
    #pragma unroll
    for (int n = 0; n < 4; ++n)
      bfr[n] = *reinterpret_cast<const bf16x8*>(Bbuf + boff + n * 16 * BK2);
    STAGE_A(Ts, bs);
    __builtin_amdgcn_s_barrier();
    __builtin_amdgcn_s_setprio(1);
    #pragma unroll
    for (int m = 0; m < 4; ++m)
      #pragma unroll
      for (int n = 0; n < 4; ++n)
        acc[m][n] = __builtin_amdgcn_mfma_f32_16x16x32_bf16(af[m], bfr[n], acc[m][n], 0, 0, 0);
    __builtin_amdgcn_s_setprio(0);
    __builtin_amdgcn_s_barrier();

    // ---- phase 1: rows 64-127 of wave half (B frags reused from regs)
    #pragma unroll
    for (int m = 0; m < 4; ++m)
      af[m] = *reinterpret_cast<const bf16x8*>(Abuf + aoff + (64 + m * 16) * BK2);
    STAGE_B(Ts, bs);
    asm volatile("s_waitcnt vmcnt(4)" ::: "memory");  // retire tile T+1 (counted, never 0)
    __builtin_amdgcn_s_barrier();
    __builtin_amdgcn_s_setprio(1);
    #pragma unroll
    for (int m = 0; m < 4; ++m)
      #pragma unroll
      for (int n = 0; n < 4; ++n)
        acc[4 + m][n] = __builtin_amdgcn_mfma_f32_16x16x32_bf16(af[m], bfr[n], acc[4 + m][n], 0, 0, 0);
    __builtin_amdgcn_s_setprio(0);
    __builtin_amdgcn_s_barrier();
  }
#undef STAGE_A
#undef STAGE_B

  // epilogue: C/D layout col=lane&15, row=(lane>>4)*4+rg (verified)
  #pragma unroll
  for (int m = 0; m < 8; ++m) {
    const int rr = n0 + wr * 128 + m * 16 + (lane >> 4) * 4;
    #pragma unroll
    for (int n = 0; n < 4; ++n) {
      const int cc = d0 + wc * 64 + n * 16 + rl;
      #pragma unroll
      for (int rg = 0; rg < 4; ++rg)
        Cb[(size_t)(rr + rg) * ND + cc] = acc[m][n][rg];
    }
  }
}

// ---- kernel 5: in-place quaternion rotation + LayerNorm over D (one block per (b,s) row)
__global__ __launch_bounds__(256) void krotln(float* __restrict__ io,
                                              const float* __restrict__ R,
                                              const float* __restrict__ gam,
                                              const float* __restrict__ bet) {
  const int t = threadIdx.x;
  float* p = io + (size_t)blockIdx.x * ND + t * 4;
  float4 v = *reinterpret_cast<const float4*>(p);
  float o0 = R[0] * v.x + R[1] * v.y + R[2]  * v.z + R[3]  * v.w;
  float o1 = R[4] * v.x + R[5] * v.y + R[6]  * v.z + R[7]  * v.w;
  float o2 = R[8] * v.x + R[9] * v.y + R[10] * v.z + R[11] * v.w;
  float o3 = R[12] * v.x + R[13] * v.y + R[14] * v.z + R[15] * v.w;
  float sm = o0 + o1 + o2 + o3;
  float sq = o0 * o0 + o1 * o1 + o2 * o2 + o3 * o3;
  #pragma unroll
  for (int off = 32; off; off >>= 1) {
    sm += __shfl_xor(sm, off);
    sq += __shfl_xor(sq, off);
  }
  __shared__ float rs[4], rq[4];
  if ((t & 63) == 0) { rs[t >> 6] = sm; rq[t >> 6] = sq; }
  __syncthreads();
  sm = rs[0] + rs[1] + rs[2] + rs[3];
  sq = rq[0] + rq[1] + rq[2] + rq[3];
  const float mean = sm * (1.0f / ND);
  const float var = sq * (1.0f / ND) - mean * mean;
  const float inv = rsqrtf(var + LN_EPS);
  const float4 gv = *reinterpret_cast<const float4*>(gam + t * 4);
  const float4 bv = *reinterpret_cast<const float4*>(bet + t * 4);
  float4 r;
  r.x = (o0 - mean) * inv * gv.x + bv.x;
  r.y = (o1 - mean) * inv * gv.y + bv.y;
  r.z = (o2 - mean) * inv * gv.z + bv.z;
  r.w = (o3 - mean) * inv * gv.w + bv.w;
  *reinterpret_cast<float4*>(p) = r;
}

extern "C" void kernel_launch(void* const* d_in, const int* in_sizes, int n_in,
                              void* d_out, int out_size, void* d_ws, size_t ws_size,
                              hipStream_t stream) {
  const float* x  = (const float*)d_in[0];
  const float* R  = (const float*)d_in[1];
  const float* fk = (const float*)d_in[2];
  const float* gm = (const float*)d_in[3];
  const float* bt = (const float*)d_in[4];
  float* out = (float*)d_out;

  char* ws = (char*)d_ws;
  unsigned short* G  = (unsigned short*)ws;                                   // 32 MiB
  unsigned short* xT = (unsigned short*)(ws + (size_t)NS * NS * 2);           // 32 MiB
  float* g = (float*)(ws + (size_t)NS * NS * 2 + (size_t)NB * ND * NS * 2);   // 16 KiB

  (void)hipFuncSetAttribute((const void*)kgemm2,
                            hipFuncAttributeMaxDynamicSharedMemorySize, 131072);

  kgcirc<<<NS, 256, 0, stream>>>(fk, g);
  kbuildG<<<NS, 256, 0, stream>>>(g, G);
  ktrans<<<dim3(NS / 64, ND / 64, NB), 256, 0, stream>>>(x, xT);
  kgemm2<<<dim3(NS / 256, ND / 256, NB), 512, 131072, stream>>>(G, xT, out);
  krotln<<<NB * NS, 256, 0, stream>>>(out, R, gm, bt);
}